// Round 1
// baseline (555.652 us; speedup 1.0000x reference)
//
#include <hip/hip_runtime.h>

typedef __bf16 bf16x8 __attribute__((ext_vector_type(8)));
typedef float f32x4 __attribute__((ext_vector_type(4)));

static __device__ __forceinline__ unsigned short f2bf(float f) {
  union { float fv; unsigned u; } v; v.fv = f;
  unsigned u = v.u;
  u += 0x7fffu + ((u >> 16) & 1u);   // round-to-nearest-even
  return (unsigned short)(u >> 16);
}

// ---- pack: W (K x 512) fp32 row-major -> bf16 K-panels P[ks][n][kk], ks=k/32 ----
__global__ __launch_bounds__(256) void pack_w(const float* __restrict__ W,
                                              unsigned short* __restrict__ P) {
  __shared__ float tile[32][65];
  const int N = 512;
  int k0 = blockIdx.x * 32, n0 = blockIdx.y * 64;
  int t = threadIdx.x;
  int nn = t & 63, kkb = t >> 6;
#pragma unroll
  for (int i = 0; i < 8; ++i) {
    int kk = kkb + i * 4;
    tile[kk][nn] = W[(size_t)(k0 + kk) * N + n0 + nn];
  }
  __syncthreads();
  size_t base = (size_t)blockIdx.x * (N * 32) + (size_t)n0 * 32;
#pragma unroll
  for (int i = 0; i < 8; ++i) {
    int e = t + i * 256;                 // 0..2047 over (n local, kk)
    P[base + e] = f2bf(tile[e & 31][e >> 5]);
  }
}

// ---- per-batch prep: gauss mask, hidden->bf16, tanh(hidden) into A2 cols 2048..2559 ----
__global__ __launch_bounds__(128) void prep_batch(
    const float* __restrict__ hidden,
    const float* __restrict__ ka1, const float* __restrict__ kb1,
    const float* __restrict__ ka2, const float* __restrict__ kb2,
    float* __restrict__ gauss,
    unsigned short* __restrict__ hid_bf,
    unsigned short* __restrict__ A2) {
  int b = blockIdx.x, t = threadIdx.x;
  __shared__ float hl[512];
  __shared__ float tt[128];
  __shared__ float pp[128];
  for (int i = t; i < 512; i += 128) {
    float v = hidden[b * 512 + i];
    hl[i] = v;
    hid_bf[b * 512 + i] = f2bf(v);
    A2[(size_t)b * 2560 + 2048 + i] = f2bf(tanhf(v));
  }
  __syncthreads();
  {
    const float* ka = (t < 64) ? ka1 : ka2;   // (512, 64)
    int lp = t & 63;
    float s = 0.f;
    for (int h = 0; h < 512; ++h) s += hl[h] * ka[h * 64 + lp];
    tt[t] = tanhf(s);
  }
  __syncthreads();
  {
    const float* kb = (t < 64) ? kb1 : kb2;   // (64, 64)
    const float* ts = (t < 64) ? tt : tt + 64;
    int l = t & 63;
    float s = 0.f;
    for (int j = 0; j < 64; ++j) s += ts[j] * kb[j * 64 + l];
    pp[t] = 8.0f / (1.0f + expf(-s));         // sigmoid * sqrt(64)
  }
  __syncthreads();
  if (t < 64) {
    float fi = (float)(t + 1);
    float r = floorf(fi * 0.125f);
    float c = floorf(fmodf(fi, 8.0f)) - 1.0f;
    float dr = r - pp[t], dc = c - pp[64 + t];
    gauss[b * 64 + t] = expf(-2.0f * (dr * dr + dc * dc));
  }
}

// ---- generic 64x64-tile bf16 MFMA GEMM: C(Mx512) = A(MxK) @ Wpanels + bias ----
__global__ __launch_bounds__(256) void gemm64(
    const unsigned short* __restrict__ A, int K,
    const unsigned short* __restrict__ Wp,
    const float* __restrict__ bias,
    float* __restrict__ C) {
  __shared__ unsigned short lA[64 * 40];   // pad 32->40 to break bank conflicts
  __shared__ unsigned short lB[64 * 40];
  int m0 = blockIdx.x * 64, n0 = blockIdx.y * 64;
  int t = threadIdx.x;
  int w = t >> 6, lane = t & 63, q = lane >> 4, l15 = lane & 15;
  f32x4 acc[4] = {};
  int arow = t >> 2, achk = (t & 3) * 8;    // 16B per thread per tile
  int nsteps = K >> 5;
  for (int ks = 0; ks < nsteps; ++ks) {
    int k0 = ks << 5;
    int4 av = *(const int4*)(A + (size_t)(m0 + arow) * K + k0 + achk);
    int4 bvv = *(const int4*)(Wp + (size_t)ks * (512 * 32) + (size_t)n0 * 32 + t * 8);
    __syncthreads();
    *(int4*)(lA + arow * 40 + achk) = av;
    *(int4*)(lB + arow * 40 + achk) = bvv;
    __syncthreads();
    bf16x8 bf = *(const bf16x8*)(lB + (w * 16 + l15) * 40 + q * 8);
#pragma unroll
    for (int mt = 0; mt < 4; ++mt) {
      bf16x8 af = *(const bf16x8*)(lA + (mt * 16 + l15) * 40 + q * 8);
      acc[mt] = __builtin_amdgcn_mfma_f32_16x16x32_bf16(af, bf, acc[mt], 0, 0, 0);
    }
  }
  float bsv = bias[n0 + w * 16 + l15];
#pragma unroll
  for (int mt = 0; mt < 4; ++mt)
#pragma unroll
    for (int j = 0; j < 4; ++j)
      C[(size_t)(m0 + mt * 16 + q * 4 + j) * 512 + n0 + w * 16 + l15] = acc[mt][j] + bsv;
}

// ---- fused: score GEMM -> tanh -> @V -> softmax -> gauss -> aw + context -> A2 ----
// one block per batch b: tile 64(L) x 512(U), K=2048, BK=32, 8 waves
__global__ __launch_bounds__(512, 2) void attn_main(
    const float* __restrict__ feat,          // (B*64, 2048) fp32
    const unsigned short* __restrict__ W1p,  // bf16 panels
    const float* __restrict__ b1,
    const float* __restrict__ hb,            // (512,512) = hidden@W2 + b2
    const float* __restrict__ V,
    const float* __restrict__ bVp,
    const float* __restrict__ gauss,
    float* __restrict__ aw_out,              // d_out + 262144
    unsigned short* __restrict__ A2) {
  __shared__ unsigned short lA[64 * 40];     //  5 KB
  __shared__ unsigned short lB[512 * 40];    // 40 KB
  __shared__ float red[64 * 8];
  __shared__ float awl[64];
  int b = blockIdx.x, t = threadIdx.x;
  int w = t >> 6, lane = t & 63, q = lane >> 4, l15 = lane & 15;
  f32x4 acc[4][4] = {};
  int arow = t >> 3, achk = t & 7;           // A: 64 rows x 32 fp32, 4 floats/thread
  const float* Ab = feat + (size_t)b * (64 * 2048);
  for (int ks = 0; ks < 64; ++ks) {
    int k0 = ks << 5;
    float4 av = *(const float4*)(Ab + (size_t)arow * 2048 + k0 + achk * 4);
    const unsigned short* bp = W1p + (size_t)ks * (512 * 32);
    int4 bv0 = *(const int4*)(bp + (size_t)t * 8);
    int4 bv1 = *(const int4*)(bp + (size_t)(t + 512) * 8);
    int4 bv2 = *(const int4*)(bp + (size_t)(t + 1024) * 8);
    int4 bv3 = *(const int4*)(bp + (size_t)(t + 1536) * 8);
    __syncthreads();
    ushort4 a4;
    a4.x = f2bf(av.x); a4.y = f2bf(av.y); a4.z = f2bf(av.z); a4.w = f2bf(av.w);
    *(ushort4*)(lA + arow * 40 + achk * 4) = a4;
    {
      int c = t;
      *(int4*)(lB + (c >> 2) * 40 + (c & 3) * 8) = bv0;
      c = t + 512;
      *(int4*)(lB + (c >> 2) * 40 + (c & 3) * 8) = bv1;
      c = t + 1024;
      *(int4*)(lB + (c >> 2) * 40 + (c & 3) * 8) = bv2;
      c = t + 1536;
      *(int4*)(lB + (c >> 2) * 40 + (c & 3) * 8) = bv3;
    }
    __syncthreads();
    bf16x8 bf[4];
#pragma unroll
    for (int nt = 0; nt < 4; ++nt)
      bf[nt] = *(const bf16x8*)(lB + (w * 64 + nt * 16 + l15) * 40 + q * 8);
#pragma unroll
    for (int mt = 0; mt < 4; ++mt) {
      bf16x8 af = *(const bf16x8*)(lA + (mt * 16 + l15) * 40 + q * 8);
#pragma unroll
      for (int nt = 0; nt < 4; ++nt)
        acc[mt][nt] = __builtin_amdgcn_mfma_f32_16x16x32_bf16(af, bf[nt], acc[mt][nt], 0, 0, 0);
    }
  }
  // epilogue: s = tanh(acc + b1 + hb); partial logits = s . V, reduce over n
  float vv[4], bb[4];
#pragma unroll
  for (int nt = 0; nt < 4; ++nt) {
    int u = w * 64 + nt * 16 + l15;
    vv[nt] = V[u];
    bb[nt] = b1[u] + hb[b * 512 + u];
  }
#pragma unroll
  for (int mt = 0; mt < 4; ++mt) {
#pragma unroll
    for (int j = 0; j < 4; ++j) {
      float p = 0.f;
#pragma unroll
      for (int nt = 0; nt < 4; ++nt)
        p += tanhf(acc[mt][nt][j] + bb[nt]) * vv[nt];
      p += __shfl_xor(p, 1);
      p += __shfl_xor(p, 2);
      p += __shfl_xor(p, 4);
      p += __shfl_xor(p, 8);
      if (l15 == 0) red[(mt * 16 + q * 4 + j) * 8 + w] = p;
    }
  }
  __syncthreads();
  if (t < 64) {   // wave 0: softmax over L=64 + gaussian mask
    float s = bVp[0];
#pragma unroll
    for (int ww = 0; ww < 8; ++ww) s += red[t * 8 + ww];
    float mx = s;
#pragma unroll
    for (int o = 1; o < 64; o <<= 1) mx = fmaxf(mx, __shfl_xor(mx, o));
    float e = expf(s - mx);
    float sm = e;
#pragma unroll
    for (int o = 1; o < 64; o <<= 1) sm += __shfl_xor(sm, o);
    float a = (e / sm) * gauss[b * 64 + t];
    awl[t] = a;
    aw_out[b * 64 + t] = a;
  }
  __syncthreads();
  // context: ctx[f] = sum_l aw[l]*feat[b,l,f]; write tanh(ctx) bf16 into A2
  float4 cacc = make_float4(0.f, 0.f, 0.f, 0.f);
  for (int l = 0; l < 64; ++l) {
    float a = awl[l];
    float4 fv = *(const float4*)(Ab + (size_t)l * 2048 + t * 4);
    cacc.x += a * fv.x; cacc.y += a * fv.y; cacc.z += a * fv.z; cacc.w += a * fv.w;
  }
  ushort4 o4;
  o4.x = f2bf(tanhf(cacc.x)); o4.y = f2bf(tanhf(cacc.y));
  o4.z = f2bf(tanhf(cacc.z)); o4.w = f2bf(tanhf(cacc.w));
  *(ushort4*)(A2 + (size_t)b * 2560 + t * 4) = o4;
}

extern "C" void kernel_launch(void* const* d_in, const int* in_sizes, int n_in,
                              void* d_out, int out_size, void* d_ws, size_t ws_size,
                              hipStream_t stream) {
  (void)in_sizes; (void)n_in; (void)out_size; (void)ws_size;
  const float* feat   = (const float*)d_in[0];
  const float* hidden = (const float*)d_in[1];
  const float* W1  = (const float*)d_in[2];
  const float* b1  = (const float*)d_in[3];
  const float* W2  = (const float*)d_in[4];
  const float* b2  = (const float*)d_in[5];
  const float* V   = (const float*)d_in[6];
  const float* bV  = (const float*)d_in[7];
  const float* W3  = (const float*)d_in[8];
  const float* b3  = (const float*)d_in[9];
  const float* ka1 = (const float*)d_in[10];
  const float* kb1 = (const float*)d_in[11];
  const float* ka2 = (const float*)d_in[12];
  const float* kb2 = (const float*)d_in[13];

  char* ws = (char*)d_ws;
  unsigned short* W1p   = (unsigned short*)(ws);              // 2 MB
  unsigned short* W2p   = (unsigned short*)(ws + 2097152);    // 0.5 MB
  unsigned short* W3p   = (unsigned short*)(ws + 2621440);    // 2.5 MB
  unsigned short* hidbf = (unsigned short*)(ws + 5242880);    // 0.5 MB
  float*          hb    = (float*)(ws + 5767168);             // 1 MB
  float*          gauss = (float*)(ws + 6815744);             // 128 KB
  unsigned short* A2    = (unsigned short*)(ws + 6946816);    // 2.5 MB
  // total ws use: 9,568,256 bytes

  float* out    = (float*)d_out;
  float* aw_out = out + 512 * 512;

  pack_w<<<dim3(64, 8), 256, 0, stream>>>(W1, W1p);
  pack_w<<<dim3(16, 8), 256, 0, stream>>>(W2, W2p);
  pack_w<<<dim3(80, 8), 256, 0, stream>>>(W3, W3p);
  prep_batch<<<512, 128, 0, stream>>>(hidden, ka1, kb1, ka2, kb2, gauss, hidbf, A2);
  gemm64<<<dim3(8, 8), 256, 0, stream>>>(hidbf, 512, W2p, b2, hb);
  attn_main<<<512, 512, 0, stream>>>(feat, W1p, b1, hb, V, bV, gauss, aw_out, A2);
  gemm64<<<dim3(8, 8), 256, 0, stream>>>(A2, 2560, W3p, b3, out);
}

// Round 2
// 542.873 us; speedup vs baseline: 1.0235x; 1.0235x over previous
//
#include <hip/hip_runtime.h>

typedef __bf16 bf16x8 __attribute__((ext_vector_type(8)));
typedef float f32x4 __attribute__((ext_vector_type(4)));

static __device__ __forceinline__ unsigned short f2bf(float f) {
  union { float fv; unsigned u; } v; v.fv = f;
  unsigned u = v.u;
  u += 0x7fffu + ((u >> 16) & 1u);   // round-to-nearest-even
  return (unsigned short)(u >> 16);
}

// ---- pack all three W (K x 512) fp32 row-major -> bf16 K-panels P[ks][n][kk] ----
__global__ __launch_bounds__(256) void pack_all(
    const float* __restrict__ W1, const float* __restrict__ W2,
    const float* __restrict__ W3,
    unsigned short* __restrict__ W1p, unsigned short* __restrict__ W2p,
    unsigned short* __restrict__ W3p) {
  __shared__ float tile[32][65];
  const int N = 512;
  const float* W; unsigned short* P; int nk;
  if (blockIdx.z == 0)      { W = W1; P = W1p; nk = 64; }
  else if (blockIdx.z == 1) { W = W2; P = W2p; nk = 16; }
  else                      { W = W3; P = W3p; nk = 80; }
  if ((int)blockIdx.x >= nk) return;
  int k0 = blockIdx.x * 32, n0 = blockIdx.y * 64;
  int t = threadIdx.x;
  int nn = t & 63, kkb = t >> 6;
#pragma unroll
  for (int i = 0; i < 8; ++i) {
    int kk = kkb + i * 4;
    tile[kk][nn] = W[(size_t)(k0 + kk) * N + n0 + nn];
  }
  __syncthreads();
  size_t base = (size_t)blockIdx.x * (N * 32) + (size_t)n0 * 32;
#pragma unroll
  for (int i = 0; i < 8; ++i) {
    int e = t + i * 256;                 // 0..2047 over (n local, kk)
    P[base + e] = f2bf(tile[e & 31][e >> 5]);
  }
}

// ---- per-batch prep: gauss mask, hidden->bf16, tanh(hidden) into A2 cols 2048..2559 ----
__global__ __launch_bounds__(128) void prep_batch(
    const float* __restrict__ hidden,
    const float* __restrict__ ka1, const float* __restrict__ kb1,
    const float* __restrict__ ka2, const float* __restrict__ kb2,
    float* __restrict__ gauss,
    unsigned short* __restrict__ hid_bf,
    unsigned short* __restrict__ A2) {
  int b = blockIdx.x, t = threadIdx.x;
  __shared__ float hl[512];
  __shared__ float tt[128];
  __shared__ float pp[128];
  for (int i = t; i < 512; i += 128) {
    float v = hidden[b * 512 + i];
    hl[i] = v;
    hid_bf[b * 512 + i] = f2bf(v);
    A2[(size_t)b * 2560 + 2048 + i] = f2bf(tanhf(v));
  }
  __syncthreads();
  {
    const float* ka = (t < 64) ? ka1 : ka2;   // (512, 64)
    int lp = t & 63;
    float s0 = 0.f, s1 = 0.f, s2 = 0.f, s3 = 0.f;
    for (int h = 0; h < 512; h += 4) {
      s0 += hl[h + 0] * ka[(h + 0) * 64 + lp];
      s1 += hl[h + 1] * ka[(h + 1) * 64 + lp];
      s2 += hl[h + 2] * ka[(h + 2) * 64 + lp];
      s3 += hl[h + 3] * ka[(h + 3) * 64 + lp];
    }
    tt[t] = tanhf((s0 + s1) + (s2 + s3));
  }
  __syncthreads();
  {
    const float* kb = (t < 64) ? kb1 : kb2;   // (64, 64)
    const float* ts = (t < 64) ? tt : tt + 64;
    int l = t & 63;
    float s = 0.f;
    for (int j = 0; j < 64; ++j) s += ts[j] * kb[j * 64 + l];
    pp[t] = 8.0f / (1.0f + expf(-s));         // sigmoid * sqrt(64)
  }
  __syncthreads();
  if (t < 64) {
    float fi = (float)(t + 1);
    float r = floorf(fi * 0.125f);
    float c = floorf(fmodf(fi, 8.0f)) - 1.0f;
    float dr = r - pp[t], dc = c - pp[64 + t];
    gauss[b * 64 + t] = expf(-2.0f * (dr * dr + dc * dc));
  }
}

// ---- generic 64x64-tile bf16 MFMA GEMM, register-prefetch pipelined ----
__global__ __launch_bounds__(256, 4) void gemm64(
    const unsigned short* __restrict__ A, int K,
    const unsigned short* __restrict__ Wp,
    const float* __restrict__ bias,
    float* __restrict__ C) {
  __shared__ unsigned short lA[64 * 40];   // pad 32->40 to break bank conflicts
  __shared__ unsigned short lB[64 * 40];
  int m0 = blockIdx.x * 64, n0 = blockIdx.y * 64;
  int t = threadIdx.x;
  int w = t >> 6, lane = t & 63, q = lane >> 4, l15 = lane & 15;
  f32x4 acc[4] = {};
  int arow = t >> 2, achk = (t & 3) * 8;    // 16B per thread per tile
  int nsteps = K >> 5;
  const unsigned short* pA = A + (size_t)(m0 + arow) * K + achk;
  const unsigned short* pB = Wp + (size_t)n0 * 32 + t * 8;
  float bsv = bias[n0 + w * 16 + l15];
  int4 av = *(const int4*)(pA);
  int4 bvv = *(const int4*)(pB);
  for (int ks = 0; ks < nsteps; ++ks) {
    __syncthreads();
    *(int4*)(lA + arow * 40 + achk) = av;
    *(int4*)(lB + arow * 40 + achk) = bvv;
    __syncthreads();
    int ksn = (ks + 1 < nsteps) ? ks + 1 : ks;
    av = *(const int4*)(pA + ksn * 32);
    bvv = *(const int4*)(pB + (size_t)ksn * (512 * 32));
    bf16x8 bf = *(const bf16x8*)(lB + (w * 16 + l15) * 40 + q * 8);
#pragma unroll
    for (int mt = 0; mt < 4; ++mt) {
      bf16x8 af = *(const bf16x8*)(lA + (mt * 16 + l15) * 40 + q * 8);
      acc[mt] = __builtin_amdgcn_mfma_f32_16x16x32_bf16(af, bf, acc[mt], 0, 0, 0);
    }
  }
#pragma unroll
  for (int mt = 0; mt < 4; ++mt)
#pragma unroll
    for (int j = 0; j < 4; ++j)
      C[(size_t)(m0 + mt * 16 + q * 4 + j) * 512 + n0 + w * 16 + l15] = acc[mt][j] + bsv;
}

// ---- fused: score GEMM -> tanh -> @V -> softmax -> gauss -> aw + context -> A2 ----
// one block per batch b: tile 64(L) x 512(U), K=2048, BK=32, 8 waves, pipelined
__global__ __launch_bounds__(512, 4) void attn_main(
    const float* __restrict__ feat,          // (B*64, 2048) fp32
    const unsigned short* __restrict__ W1p,  // bf16 panels
    const float* __restrict__ b1,
    const float* __restrict__ hb,            // (512,512) = hidden@W2 + b2
    const float* __restrict__ V,
    const float* __restrict__ bVp,
    const float* __restrict__ gauss,
    float* __restrict__ aw_out,              // d_out + 262144
    unsigned short* __restrict__ A2) {
  __shared__ unsigned short lA[64 * 40];     //  5 KB
  __shared__ unsigned short lB[512 * 40];    // 40 KB
  __shared__ float red[64 * 8];
  __shared__ float awl[64];
  int b = blockIdx.x, t = threadIdx.x;
  int w = t >> 6, lane = t & 63, q = lane >> 4, l15 = lane & 15;
  f32x4 acc[4][4] = {};
  int arow = t >> 3, achk = t & 7;           // A: 64 rows x 32 fp32, 4 floats/thread
  const float* Ab = feat + (size_t)b * (64 * 2048);
  const float* pA = Ab + (size_t)arow * 2048 + achk * 4;
  const unsigned short* pB = W1p + (size_t)t * 8;

  // hoist epilogue operands (tiny, L2-resident) before the hot loop
  float vv[4], bb[4];
#pragma unroll
  for (int nt = 0; nt < 4; ++nt) {
    int u = w * 64 + nt * 16 + l15;
    vv[nt] = V[u];
    bb[nt] = b1[u] + hb[b * 512 + u];
  }
  float gs = (t < 64) ? gauss[b * 64 + t] : 0.f;
  float bV0 = bVp[0];

  // prefetch step 0
  float4 av = *(const float4*)(pA);
  int4 bv0 = *(const int4*)(pB);
  int4 bv1 = *(const int4*)(pB + 4096);
  int4 bv2 = *(const int4*)(pB + 8192);
  int4 bv3 = *(const int4*)(pB + 12288);

  for (int ks = 0; ks < 64; ++ks) {
    __syncthreads();
    ushort4 a4;
    a4.x = f2bf(av.x); a4.y = f2bf(av.y); a4.z = f2bf(av.z); a4.w = f2bf(av.w);
    *(ushort4*)(lA + arow * 40 + achk * 4) = a4;
    {
      int c = t;
      *(int4*)(lB + (c >> 2) * 40 + (c & 3) * 8) = bv0;
      c = t + 512;
      *(int4*)(lB + (c >> 2) * 40 + (c & 3) * 8) = bv1;
      c = t + 1024;
      *(int4*)(lB + (c >> 2) * 40 + (c & 3) * 8) = bv2;
      c = t + 1536;
      *(int4*)(lB + (c >> 2) * 40 + (c & 3) * 8) = bv3;
    }
    __syncthreads();
    // issue next step's loads BEFORE the MFMA phase so latency hides under it
    {
      int ksn = (ks < 63) ? ks + 1 : ks;
      const unsigned short* bp = pB + (size_t)ksn * (512 * 32);
      av  = *(const float4*)(pA + ksn * 32);
      bv0 = *(const int4*)(bp);
      bv1 = *(const int4*)(bp + 4096);
      bv2 = *(const int4*)(bp + 8192);
      bv3 = *(const int4*)(bp + 12288);
    }
    bf16x8 bf[4];
#pragma unroll
    for (int nt = 0; nt < 4; ++nt)
      bf[nt] = *(const bf16x8*)(lB + (w * 64 + nt * 16 + l15) * 40 + q * 8);
#pragma unroll
    for (int mt = 0; mt < 4; ++mt) {
      bf16x8 af = *(const bf16x8*)(lA + (mt * 16 + l15) * 40 + q * 8);
#pragma unroll
      for (int nt = 0; nt < 4; ++nt)
        acc[mt][nt] = __builtin_amdgcn_mfma_f32_16x16x32_bf16(af, bf[nt], acc[mt][nt], 0, 0, 0);
    }
  }
  // epilogue: s = tanh(acc + b1 + hb); partial logits = s . V, reduce over n
#pragma unroll
  for (int mt = 0; mt < 4; ++mt) {
#pragma unroll
    for (int j = 0; j < 4; ++j) {
      float p = 0.f;
#pragma unroll
      for (int nt = 0; nt < 4; ++nt)
        p += tanhf(acc[mt][nt][j] + bb[nt]) * vv[nt];
      p += __shfl_xor(p, 1);
      p += __shfl_xor(p, 2);
      p += __shfl_xor(p, 4);
      p += __shfl_xor(p, 8);
      if (l15 == 0) red[(mt * 16 + q * 4 + j) * 8 + w] = p;
    }
  }
  __syncthreads();
  if (t < 64) {   // wave 0: softmax over L=64 + gaussian mask
    float s = bV0;
#pragma unroll
    for (int ww = 0; ww < 8; ++ww) s += red[t * 8 + ww];
    float mx = s;
#pragma unroll
    for (int o = 1; o < 64; o <<= 1) mx = fmaxf(mx, __shfl_xor(mx, o));
    float e = expf(s - mx);
    float sm = e;
#pragma unroll
    for (int o = 1; o < 64; o <<= 1) sm += __shfl_xor(sm, o);
    float a = (e / sm) * gs;
    awl[t] = a;
    aw_out[b * 64 + t] = a;
  }
  __syncthreads();
  // context: ctx[f] = sum_l aw[l]*feat[b,l,f]; write tanh(ctx) bf16 into A2
  float4 cacc = make_float4(0.f, 0.f, 0.f, 0.f);
  for (int l = 0; l < 64; ++l) {
    float a = awl[l];
    float4 fv = *(const float4*)(Ab + (size_t)l * 2048 + t * 4);
    cacc.x += a * fv.x; cacc.y += a * fv.y; cacc.z += a * fv.z; cacc.w += a * fv.w;
  }
  ushort4 o4;
  o4.x = f2bf(tanhf(cacc.x)); o4.y = f2bf(tanhf(cacc.y));
  o4.z = f2bf(tanhf(cacc.z)); o4.w = f2bf(tanhf(cacc.w));
  *(ushort4*)(A2 + (size_t)b * 2560 + t * 4) = o4;
}

extern "C" void kernel_launch(void* const* d_in, const int* in_sizes, int n_in,
                              void* d_out, int out_size, void* d_ws, size_t ws_size,
                              hipStream_t stream) {
  (void)in_sizes; (void)n_in; (void)out_size; (void)ws_size;
  const float* feat   = (const float*)d_in[0];
  const float* hidden = (const float*)d_in[1];
  const float* W1  = (const float*)d_in[2];
  const float* b1  = (const float*)d_in[3];
  const float* W2  = (const float*)d_in[4];
  const float* b2  = (const float*)d_in[5];
  const float* V   = (const float*)d_in[6];
  const float* bV  = (const float*)d_in[7];
  const float* W3  = (const float*)d_in[8];
  const float* b3  = (const float*)d_in[9];
  const float* ka1 = (const float*)d_in[10];
  const float* kb1 = (const float*)d_in[11];
  const float* ka2 = (const float*)d_in[12];
  const float* kb2 = (const float*)d_in[13];

  char* ws = (char*)d_ws;
  unsigned short* W1p   = (unsigned short*)(ws);              // 2 MB
  unsigned short* W2p   = (unsigned short*)(ws + 2097152);    // 0.5 MB
  unsigned short* W3p   = (unsigned short*)(ws + 2621440);    // 2.5 MB
  unsigned short* hidbf = (unsigned short*)(ws + 5242880);    // 0.5 MB
  float*          hb    = (float*)(ws + 5767168);             // 1 MB
  float*          gauss = (float*)(ws + 6815744);             // 128 KB
  unsigned short* A2    = (unsigned short*)(ws + 6946816);    // 2.5 MB
  // total ws use: 9,568,256 bytes

  float* out    = (float*)d_out;
  float* aw_out = out + 512 * 512;

  pack_all<<<dim3(80, 8, 3), 256, 0, stream>>>(W1, W2, W3, W1p, W2p, W3p);
  prep_batch<<<512, 128, 0, stream>>>(hidden, ka1, kb1, ka2, kb2, gauss, hidbf, A2);
  gemm64<<<dim3(8, 8), 256, 0, stream>>>(hidbf, 512, W2p, b2, hb);
  attn_main<<<512, 512, 0, stream>>>(feat, W1p, b1, hb, V, bV, gauss, aw_out, A2);
  gemm64<<<dim3(8, 8), 256, 0, stream>>>(A2, 2560, W3p, b3, out);
}

// Round 3
// 507.811 us; speedup vs baseline: 1.0942x; 1.0690x over previous
//
#include <hip/hip_runtime.h>

typedef __bf16 bf16x8 __attribute__((ext_vector_type(8)));
typedef float f32x4 __attribute__((ext_vector_type(4)));

static __device__ __forceinline__ unsigned short f2bf(float f) {
  union { float fv; unsigned u; } v; v.fv = f;
  unsigned u = v.u;
  u += 0x7fffu + ((u >> 16) & 1u);   // round-to-nearest-even
  return (unsigned short)(u >> 16);
}

static __device__ __forceinline__ float fast_tanh(float x) {
  x = fminf(fmaxf(x, -15.f), 15.f);
  float ex = __expf(2.f * x);
  return (ex - 1.f) / (ex + 1.f);
}

// ---- pack W (K x 512) fp32 row-major -> bf16 fragment-major P[k/8][n][k%8] ----
__global__ __launch_bounds__(256) void pack_all(
    const float* __restrict__ W1, const float* __restrict__ W2,
    const float* __restrict__ W3,
    unsigned short* __restrict__ W1p, unsigned short* __restrict__ W2p,
    unsigned short* __restrict__ W3p) {
  __shared__ float tile[32][65];
  const int N = 512;
  const float* W; unsigned short* P; int nk;
  if (blockIdx.z == 0)      { W = W1; P = W1p; nk = 64; }
  else if (blockIdx.z == 1) { W = W2; P = W2p; nk = 16; }
  else                      { W = W3; P = W3p; nk = 80; }
  if ((int)blockIdx.x >= nk) return;
  int k0 = blockIdx.x * 32, n0 = blockIdx.y * 64;
  int t = threadIdx.x;
  int nn = t & 63, kkb = t >> 6;
#pragma unroll
  for (int i = 0; i < 8; ++i) {
    int kk = kkb + i * 4;
    tile[kk][nn] = W[(size_t)(k0 + kk) * N + n0 + nn];
  }
  __syncthreads();
#pragma unroll
  for (int i = 0; i < 8; ++i) {
    int e = t + i * 256;                 // 0..2047
    int k8 = e & 7, n = (e >> 3) & 63, c = e >> 9;   // c = k-chunk within 32 (0..3)
    size_t dst = (size_t)((k0 >> 3) + c) * 4096 + (size_t)(n0 + n) * 8 + k8;
    P[dst] = f2bf(tile[c * 8 + k8][n]);
  }
}

// ---- per-batch prep: gauss mask, hidden->bf16, tanh(hidden) into A2 cols 2048..2559 ----
__global__ __launch_bounds__(128) void prep_batch(
    const float* __restrict__ hidden,
    const float* __restrict__ ka1, const float* __restrict__ kb1,
    const float* __restrict__ ka2, const float* __restrict__ kb2,
    float* __restrict__ gauss,
    unsigned short* __restrict__ hid_bf,
    unsigned short* __restrict__ A2) {
  int b = blockIdx.x, t = threadIdx.x;
  __shared__ float hl[512];
  __shared__ float tt[128];
  __shared__ float pp[128];
  for (int i = t; i < 512; i += 128) {
    float v = hidden[b * 512 + i];
    hl[i] = v;
    hid_bf[b * 512 + i] = f2bf(v);
    A2[(size_t)b * 2560 + 2048 + i] = f2bf(tanhf(v));
  }
  __syncthreads();
  {
    const float* ka = (t < 64) ? ka1 : ka2;   // (512, 64)
    int lp = t & 63;
    float s0 = 0.f, s1 = 0.f, s2 = 0.f, s3 = 0.f;
    for (int h = 0; h < 512; h += 4) {
      s0 += hl[h + 0] * ka[(h + 0) * 64 + lp];
      s1 += hl[h + 1] * ka[(h + 1) * 64 + lp];
      s2 += hl[h + 2] * ka[(h + 2) * 64 + lp];
      s3 += hl[h + 3] * ka[(h + 3) * 64 + lp];
    }
    tt[t] = tanhf((s0 + s1) + (s2 + s3));
  }
  __syncthreads();
  {
    const float* kb = (t < 64) ? kb1 : kb2;   // (64, 64)
    const float* ts = (t < 64) ? tt : tt + 64;
    int l = t & 63;
    float s = 0.f;
    for (int j = 0; j < 64; ++j) s += ts[j] * kb[j * 64 + l];
    pp[t] = 8.0f / (1.0f + expf(-s));         // sigmoid * sqrt(64)
  }
  __syncthreads();
  if (t < 64) {
    float fi = (float)(t + 1);
    float r = floorf(fi * 0.125f);
    float c = floorf(fmodf(fi, 8.0f)) - 1.0f;
    float dr = r - pp[t], dc = c - pp[64 + t];
    gauss[b * 64 + t] = expf(-2.0f * (dr * dr + dc * dc));
  }
}

// ---- 64x64-tile bf16 MFMA GEMM, B direct from L2 fragment-layout, optional K-split ----
// bias != nullptr: C[m][n] = acc + bias[n].  bias == nullptr: partial out at C + z*262144.
__global__ __launch_bounds__(256, 4) void gemm64d(
    const unsigned short* __restrict__ A, int lda, int k8_stride, int nsteps,
    const unsigned short* __restrict__ Wp,
    const float* __restrict__ bias,
    float* __restrict__ C) {
  __shared__ unsigned short lA[64 * 40];
  int m0 = blockIdx.x * 64, n0 = blockIdx.y * 64;
  int z = blockIdx.z;
  int k8 = z * k8_stride;
  int t = threadIdx.x;
  int w = t >> 6, lane = t & 63, q = lane >> 4, l15 = lane & 15;
  f32x4 acc[4] = {};
  int arow = t >> 2, achk = (t & 3) * 8;
  const unsigned short* pA = A + (size_t)(m0 + arow) * lda + (size_t)k8 * 8 + achk;
  const unsigned short* pB = Wp + ((size_t)(k8 + q) * 512 + n0 + w * 16 + l15) * 8;
  int4 av = *(const int4*)(pA);
  int4 bv = *(const int4*)(pB);
  for (int ks = 0; ks < nsteps; ++ks) {
    __syncthreads();
    *(int4*)(lA + arow * 40 + achk) = av;
    __syncthreads();
    int ksn = (ks + 1 < nsteps) ? ks + 1 : ks;
    av = *(const int4*)(pA + ksn * 32);
    int4 bn = *(const int4*)(pB + (size_t)ksn * 16384);
    bf16x8 bf = *(const bf16x8*)&bv;
#pragma unroll
    for (int mt = 0; mt < 4; ++mt) {
      bf16x8 af = *(const bf16x8*)(lA + (mt * 16 + l15) * 40 + q * 8);
      acc[mt] = __builtin_amdgcn_mfma_f32_16x16x32_bf16(af, bf, acc[mt], 0, 0, 0);
    }
    bv = bn;
  }
  int col = n0 + w * 16 + l15;
  if (bias) {
    float bsv = bias[col];
#pragma unroll
    for (int mt = 0; mt < 4; ++mt)
#pragma unroll
      for (int j = 0; j < 4; ++j)
        C[(size_t)(m0 + mt * 16 + q * 4 + j) * 512 + col] = acc[mt][j] + bsv;
  } else {
    float* Cp = C + (size_t)z * 262144;
#pragma unroll
    for (int mt = 0; mt < 4; ++mt)
#pragma unroll
      for (int j = 0; j < 4; ++j)
        Cp[(size_t)(m0 + mt * 16 + q * 4 + j) * 512 + col] = acc[mt][j];
  }
}

// ---- reduce 4 K-split partials + bias -> out ----
__global__ __launch_bounds__(256) void reduce4(const float* __restrict__ part,
                                               const float* __restrict__ b3,
                                               float* __restrict__ out) {
  int i = blockIdx.x * 256 + threadIdx.x;   // float4 index, 65536 total
  int base = i * 4;
  int n = base & 511;
  float4 p0 = *(const float4*)(part + base);
  float4 p1 = *(const float4*)(part + 262144 + base);
  float4 p2 = *(const float4*)(part + 524288 + base);
  float4 p3 = *(const float4*)(part + 786432 + base);
  float4 bv = *(const float4*)(b3 + n);
  float4 r;
  r.x = p0.x + p1.x + p2.x + p3.x + bv.x;
  r.y = p0.y + p1.y + p2.y + p3.y + bv.y;
  r.z = p0.z + p1.z + p2.z + p3.z + bv.z;
  r.w = p0.w + p1.w + p2.w + p3.w + bv.w;
  *(float4*)(out + base) = r;
}

// ---- fused: score GEMM -> tanh -> @V -> softmax -> gauss -> aw + context -> A2 ----
// one block per batch: 256 thr (4 waves), tile 64(L) x 512(U), wave = 64x128,
// B frags direct from L2 (fragment-major layout), A LDS double-buffered.
__global__ __launch_bounds__(256, 2) void attn_main(
    const float* __restrict__ feat,          // (B*64, 2048) fp32
    const unsigned short* __restrict__ W1p,  // bf16 fragment-major
    const float* __restrict__ b1,
    const float* __restrict__ hb,            // (512,512) = hidden@W2 + b2
    const float* __restrict__ V,
    const float* __restrict__ bVp,
    const float* __restrict__ gauss,
    float* __restrict__ aw_out,
    unsigned short* __restrict__ A2) {
  __shared__ unsigned short lA[2][64 * 40];  // 10.2 KB
  __shared__ float red[64 * 4];
  __shared__ float awl[64];
  int b = blockIdx.x, t = threadIdx.x;
  int w = t >> 6, lane = t & 63, q = lane >> 4, l15 = lane & 15;
  f32x4 acc[4][8] = {};
  int row0 = t >> 3, ch0 = t & 7;            // A stage: rows row0 & row0+32, 16B chunks
  const float* Ab = feat + (size_t)b * (64 * 2048);
  const float* pA0 = Ab + row0 * 2048 + ch0 * 4;
  const float* pA1 = pA0 + 32 * 2048;
  const unsigned short* pB = W1p + ((size_t)q * 512 + w * 128 + l15) * 8;
  int wA = row0 * 40 + ch0 * 4;

  // hoisted epilogue operands (tiny, L2-resident)
  float vv[8], bb[8];
#pragma unroll
  for (int nt = 0; nt < 8; ++nt) {
    int u = w * 128 + nt * 16 + l15;
    vv[nt] = V[u];
    bb[nt] = b1[u] + hb[b * 512 + u];
  }
  float gs = (t < 64) ? gauss[b * 64 + t] : 0.f;
  float bV0 = bVp[0];

  auto mmaStep = [&](int buf, const int4* B) {
#pragma unroll
    for (int mt = 0; mt < 4; ++mt) {
      bf16x8 af = *(const bf16x8*)(&lA[buf][(mt * 16 + l15) * 40 + q * 8]);
#pragma unroll
      for (int nt = 0; nt < 8; ++nt)
        acc[mt][nt] = __builtin_amdgcn_mfma_f32_16x16x32_bf16(
            af, *(const bf16x8*)&B[nt], acc[mt][nt], 0, 0, 0);
    }
  };
  auto stage = [&](int buf, const float4& x0, const float4& x1) {
    ushort4 u0, u1;
    u0.x = f2bf(x0.x); u0.y = f2bf(x0.y); u0.z = f2bf(x0.z); u0.w = f2bf(x0.w);
    u1.x = f2bf(x1.x); u1.y = f2bf(x1.y); u1.z = f2bf(x1.z); u1.w = f2bf(x1.w);
    *(ushort4*)(&lA[buf][wA]) = u0;
    *(ushort4*)(&lA[buf][wA + 1280]) = u1;
  };

  int4 bc[8], bn[8];
  float4 a0, a1, na0, na1;
  // preamble: stage step 0, prefetch step 1
  a0 = *(const float4*)(pA0);
  a1 = *(const float4*)(pA1);
#pragma unroll
  for (int nt = 0; nt < 8; ++nt) bc[nt] = *(const int4*)(pB + nt * 128);
  stage(0, a0, a1);
  na0 = *(const float4*)(pA0 + 32);
  na1 = *(const float4*)(pA1 + 32);
#pragma unroll
  for (int nt = 0; nt < 8; ++nt) bn[nt] = *(const int4*)(pB + 16384 + nt * 128);
  __syncthreads();

  for (int s2 = 0; s2 < 32; ++s2) {
    int s = 2 * s2;
    // even step s: compute on buf0 with bc=B(s); stage A(s+1)->buf1; fetch A(s+2), B(s+2)
    stage(1, na0, na1);
    {
      int kf = (s + 2 < 64) ? s + 2 : 63;
      a0 = *(const float4*)(pA0 + kf * 32);
      a1 = *(const float4*)(pA1 + kf * 32);
    }
    mmaStep(0, bc);
    {
      int kf = (s + 2 < 64) ? s + 2 : 63;
      const unsigned short* bp = pB + (size_t)kf * 16384;
#pragma unroll
      for (int nt = 0; nt < 8; ++nt) bc[nt] = *(const int4*)(bp + nt * 128);
    }
    __syncthreads();
    // odd step s+1: compute on buf1 with bn=B(s+1); stage A(s+2)->buf0; fetch A(s+3), B(s+3)
    stage(0, a0, a1);
    {
      int kf = (s + 3 < 64) ? s + 3 : 63;
      na0 = *(const float4*)(pA0 + kf * 32);
      na1 = *(const float4*)(pA1 + kf * 32);
    }
    mmaStep(1, bn);
    {
      int kf = (s + 3 < 64) ? s + 3 : 63;
      const unsigned short* bp = pB + (size_t)kf * 16384;
#pragma unroll
      for (int nt = 0; nt < 8; ++nt) bn[nt] = *(const int4*)(bp + nt * 128);
    }
    __syncthreads();
  }

  // epilogue: logits = sum_u tanh(acc + b1 + hb) * V[u]
#pragma unroll
  for (int mt = 0; mt < 4; ++mt) {
#pragma unroll
    for (int j = 0; j < 4; ++j) {
      float p = 0.f;
#pragma unroll
      for (int nt = 0; nt < 8; ++nt)
        p += fast_tanh(acc[mt][nt][j] + bb[nt]) * vv[nt];
      p += __shfl_xor(p, 1);
      p += __shfl_xor(p, 2);
      p += __shfl_xor(p, 4);
      p += __shfl_xor(p, 8);
      if (l15 == 0) red[(mt * 16 + q * 4 + j) * 4 + w] = p;
    }
  }
  __syncthreads();
  if (t < 64) {   // wave 0: softmax over L=64 + gaussian mask
    float s = bV0 + red[t * 4] + red[t * 4 + 1] + red[t * 4 + 2] + red[t * 4 + 3];
    float mx = s;
#pragma unroll
    for (int o = 1; o < 64; o <<= 1) mx = fmaxf(mx, __shfl_xor(mx, o));
    float e = __expf(s - mx);
    float sm = e;
#pragma unroll
    for (int o = 1; o < 64; o <<= 1) sm += __shfl_xor(sm, o);
    float a = (e / sm) * gs;
    awl[t] = a;
    aw_out[b * 64 + t] = a;
  }
  __syncthreads();
  // context: 8 cols per thread; write tanh(ctx) bf16 into A2
  float4 c0 = make_float4(0.f, 0.f, 0.f, 0.f);
  float4 c1 = make_float4(0.f, 0.f, 0.f, 0.f);
  const float* pF = Ab + t * 8;
  for (int l = 0; l < 64; ++l) {
    float a = awl[l];
    float4 f0 = *(const float4*)(pF + l * 2048);
    float4 f1 = *(const float4*)(pF + l * 2048 + 4);
    c0.x += a * f0.x; c0.y += a * f0.y; c0.z += a * f0.z; c0.w += a * f0.w;
    c1.x += a * f1.x; c1.y += a * f1.y; c1.z += a * f1.z; c1.w += a * f1.w;
  }
  ushort4 o0, o1;
  o0.x = f2bf(fast_tanh(c0.x)); o0.y = f2bf(fast_tanh(c0.y));
  o0.z = f2bf(fast_tanh(c0.z)); o0.w = f2bf(fast_tanh(c0.w));
  o1.x = f2bf(fast_tanh(c1.x)); o1.y = f2bf(fast_tanh(c1.y));
  o1.z = f2bf(fast_tanh(c1.z)); o1.w = f2bf(fast_tanh(c1.w));
  *(ushort4*)(A2 + (size_t)b * 2560 + t * 8) = o0;
  *(ushort4*)(A2 + (size_t)b * 2560 + t * 8 + 4) = o1;
}

extern "C" void kernel_launch(void* const* d_in, const int* in_sizes, int n_in,
                              void* d_out, int out_size, void* d_ws, size_t ws_size,
                              hipStream_t stream) {
  (void)in_sizes; (void)n_in; (void)out_size; (void)ws_size;
  const float* feat   = (const float*)d_in[0];
  const float* hidden = (const float*)d_in[1];
  const float* W1  = (const float*)d_in[2];
  const float* b1  = (const float*)d_in[3];
  const float* W2  = (const float*)d_in[4];
  const float* b2  = (const float*)d_in[5];
  const float* V   = (const float*)d_in[6];
  const float* bV  = (const float*)d_in[7];
  const float* W3  = (const float*)d_in[8];
  const float* b3  = (const float*)d_in[9];
  const float* ka1 = (const float*)d_in[10];
  const float* kb1 = (const float*)d_in[11];
  const float* ka2 = (const float*)d_in[12];
  const float* kb2 = (const float*)d_in[13];

  char* ws = (char*)d_ws;
  // long-lived:
  unsigned short* W3p   = (unsigned short*)(ws);              // 2.5 MB  [0, 2621440)
  unsigned short* A2    = (unsigned short*)(ws + 2621440);    // 2.5 MB  [2621440, 5242880)
  // transient (dead before final GEMM):
  unsigned short* W1p   = (unsigned short*)(ws + 5242880);    // 2 MB
  unsigned short* W2p   = (unsigned short*)(ws + 7340032);    // 0.5 MB
  unsigned short* hidbf = (unsigned short*)(ws + 7864320);    // 0.5 MB
  float*          hb    = (float*)(ws + 8388608);             // 1 MB
  float*          gauss = (float*)(ws + 9437184);             // 128 KB -> high water 9,568,256
  // part overlaps W1p/W2p/hidbf/hb (all dead by final GEMM): 4 MB
  float*          part  = (float*)(ws + 5242880);

  float* out    = (float*)d_out;
  float* aw_out = out + 512 * 512;

  pack_all<<<dim3(80, 8, 3), 256, 0, stream>>>(W1, W2, W3, W1p, W2p, W3p);
  prep_batch<<<512, 128, 0, stream>>>(hidden, ka1, kb1, ka2, kb2, gauss, hidbf, A2);
  gemm64d<<<dim3(8, 8, 1), 256, 0, stream>>>(hidbf, 512, 0, 16, W2p, b2, hb);
  attn_main<<<512, 256, 0, stream>>>(feat, W1p, b1, hb, V, bV, gauss, aw_out, A2);
  gemm64d<<<dim3(8, 8, 4), 256, 0, stream>>>(A2, 2560, 80, 20, W3p, nullptr, part);
  reduce4<<<256, 256, 0, stream>>>(part, b3, out);
}